// Round 18
// baseline (125.594 us; speedup 1.0000x reference)
//
#include <hip/hip_runtime.h>
#include <hip/hip_bf16.h>
#include <stdint.h>

#define FEAT 1024
#define NALL 1000
#define NCLS 100

typedef __attribute__((ext_vector_type(8))) short short8;
typedef __attribute__((ext_vector_type(4))) float f32x4;
typedef __attribute__((ext_vector_type(4))) unsigned short us4;

__device__ __forceinline__ unsigned short f2bf(float f) {
    union { float f; uint32_t u; } v; v.f = f;
    uint32_t u = v.u;
    return (unsigned short)((u + 0x7FFFu + ((u >> 16) & 1u)) >> 16);
}

__device__ __forceinline__ void gload16(const void* g, void* l) {
    __builtin_amdgcn_global_load_lds((__attribute__((address_space(1))) void*)g,
                                     (__attribute__((address_space(3))) void*)l,
                                     16, 0, 0);
}

// K1 (merged prep): blocks [0,4096): x -> bf16 + row sum-sq
//                   blocks [4096,5120): protos -> bf16 (pad rows 1000.. = 0)
//                   blocks [5120,6144): enc_w transpose -> bf16 wt[n][k]=w[k][n]
__global__ __launch_bounds__(256) void k_prep_all(const float* __restrict__ x,
                                                  unsigned short* __restrict__ xb,
                                                  float* __restrict__ xsq,
                                                  const float* __restrict__ p,
                                                  unsigned short* __restrict__ pb,
                                                  const float* __restrict__ w,
                                                  unsigned short* __restrict__ wt) {
    __shared__ float tile[32][33];
    int b = blockIdx.x;
    if (b < 4096) {
        int row = b * 4 + (threadIdx.x >> 6);
        int lane = threadIdx.x & 63;
        const float4* xr = (const float4*)(x + (size_t)row * FEAT);
        float s = 0.f;
#pragma unroll
        for (int i = 0; i < 4; ++i) {
            float4 v = xr[lane + i * 64];
            s += v.x * v.x + v.y * v.y + v.z * v.z + v.w * v.w;
            us4 o;
            o[0] = f2bf(v.x); o[1] = f2bf(v.y); o[2] = f2bf(v.z); o[3] = f2bf(v.w);
            *(us4*)(xb + (size_t)row * FEAT + (size_t)(lane + i * 64) * 4) = o;
        }
#pragma unroll
        for (int off = 32; off; off >>= 1) s += __shfl_xor(s, off);
        if (lane == 0) xsq[row] = s;
    } else if (b < 5120) {
        int row = b - 4096, t = threadIdx.x;
        us4 o;
        if (row < NALL) {
            float4 v = ((const float4*)(p + (size_t)row * FEAT))[t];
            o[0] = f2bf(v.x); o[1] = f2bf(v.y); o[2] = f2bf(v.z); o[3] = f2bf(v.w);
        } else {
            o[0] = 0; o[1] = 0; o[2] = 0; o[3] = 0;
        }
        *(us4*)(pb + (size_t)row * FEAT + (size_t)t * 4) = o;
    } else {
        int bb = b - 5120;
        int bx = bb & 31, by = bb >> 5;
        int tx = threadIdx.x & 31, ty = threadIdx.x >> 5;
#pragma unroll
        for (int i = 0; i < 4; ++i) {
            int r = by * 32 + ty + i * 8;
            tile[ty + i * 8][tx] = w[(size_t)r * FEAT + bx * 32 + tx];
        }
        __syncthreads();
#pragma unroll
        for (int i = 0; i < 4; ++i) {
            int r = bx * 32 + ty + i * 8;
            wt[(size_t)r * FEAT + by * 32 + tx] = f2bf(tile[tx][ty + i * 8]);
        }
    }
}

// K2: encoder GEMM ep = protos @ enc_w + b — 64x64 tiles, 256 blocks, with
// FUSED psq (bf16-rounded squares, shfl-reduced, one atomicAdd/row/wave).
// epb rows class-major permuted: n' = (n%100)*10 + n/100.
__global__ __launch_bounds__(256) void k_enc_gemm(const unsigned short* __restrict__ A,
                                                  const unsigned short* __restrict__ B,
                                                  const float* __restrict__ bias,
                                                  unsigned short* __restrict__ epb,
                                                  float* __restrict__ psq) {
    __shared__ __align__(16) char smem[16384];   // A [64][64] @0, B [64][64] @8192
    int bm0 = (blockIdx.x >> 4) * 64;
    int bn0 = (blockIdx.x & 15) * 64;
    int tid = threadIdx.x, lane = tid & 63, wid = tid >> 6;
    int wm = wid >> 1, wn = wid & 1;
    int ls = lane >> 4, lf = lane & 15;
    f32x4 acc[2][2] = {};
    for (int k0 = 0; k0 < FEAT; k0 += 64) {
        __syncthreads();
#pragma unroll
        for (int i = 0; i < 2; ++i) {
            int ci = wid + i * 4;
            int r = ci * 8 + (lane >> 3), c = (lane & 7) * 8;
            gload16(A + (size_t)(bm0 + r) * FEAT + k0 + c, smem + ci * 1024);
            gload16(B + (size_t)(bn0 + r) * FEAT + k0 + c, smem + 8192 + ci * 1024);
        }
        __syncthreads();
#pragma unroll
        for (int kk = 0; kk < 64; kk += 32) {
            short8 a[2], b[2];
#pragma unroll
            for (int f = 0; f < 2; ++f) {
                a[f] = *(const short8*)(smem + (wm * 32 + f * 16 + lf) * 128 + (kk + ls * 8) * 2);
                b[f] = *(const short8*)(smem + 8192 + (wn * 32 + f * 16 + lf) * 128 + (kk + ls * 8) * 2);
            }
#pragma unroll
            for (int fm = 0; fm < 2; ++fm)
#pragma unroll
                for (int fn = 0; fn < 2; ++fn)
                    acc[fm][fn] = __builtin_amdgcn_mfma_f32_16x16x32_bf16(a[fm], b[fn], acc[fm][fn], 0, 0, 0);
        }
    }
    int tr = ls * 4, tc = lf;
    float sq[2][4] = {};
#pragma unroll
    for (int fn = 0; fn < 2; ++fn) {
        int col = bn0 + wn * 32 + fn * 16 + tc;
        float bb = bias[col];
#pragma unroll
        for (int fm = 0; fm < 2; ++fm) {
#pragma unroll
            for (int r = 0; r < 4; ++r) {
                int row = bm0 + wm * 32 + fm * 16 + tr + r;
                if (row < NALL) {
                    unsigned short us = f2bf(acc[fm][fn][r] + bb);
                    union { uint32_t u; float f; } c; c.u = ((uint32_t)us) << 16;
                    sq[fm][r] += c.f * c.f;
                    int pr = (row % 100) * 10 + row / 100;
                    epb[(size_t)pr * FEAT + col] = us;
                }
            }
        }
    }
#pragma unroll
    for (int fm = 0; fm < 2; ++fm)
#pragma unroll
        for (int r = 0; r < 4; ++r) {
            float s = sq[fm][r];
            s += __shfl_xor(s, 1); s += __shfl_xor(s, 2);
            s += __shfl_xor(s, 4); s += __shfl_xor(s, 8);
            int row = bm0 + wm * 32 + fm * 16 + tr + r;
            if (lf == 0 && row < NALL) {
                int pr = (row % 100) * 10 + row / 100;
                atomicAdd(psq + pr, s);
            }
        }
}

// K3: main GEMM + fused sqrt + min-over-10 — A-IN-REGISTERS, LDS-traffic cut.
// BM=128, BN=80, BK=64, 4 waves 4Mx1N, acc[2][5].
//  - A operand direct global->VGPR, SOFTWARE-PIPELINED (aC/aN): aN(t+1) issued
//    at tile start, consumed next tile. Removes 4 of 14 ds_read_b128/wave/tile
//    AND all A staging writes (LDS-read pipe was ~33 us of r12's 63).
//  - B-only LDS, double-buffered (2 x 10 KB), ONE __syncthreads per tile after
//    the MFMA cluster.
//  - BARE launch_bounds(256): r14 ran this structure under (256,4)'s 64-reg cap,
//    which forced the RA to defeat the aN pipeline (needs ~100 regs). 22 KB LDS
//    keeps >=4 blocks/CU at <=128 total regs.
// 13 N-tiles (last at bn0=920, overlap cols identical). Grid 1664.
__global__ __launch_bounds__(256) void k_main(const unsigned short* __restrict__ xb,
                                              const unsigned short* __restrict__ epb,
                                              const float* __restrict__ xsq,
                                              const float* __restrict__ psq,
                                              float* __restrict__ out) {
    __shared__ __align__(16) char smem[22016];
    // loop: B buf0 @0, buf1 @10240; epilogue: dls[64][81] f32 @0 (20736 B)
    // persistent: xsq_s @20992 (512 B), psq_s @21504 (320 B)
    const int bid = blockIdx.x;                       // 1664 blocks
    const int swz = (bid & 7) * 208 + (bid >> 3);     // XCD swizzle (1664 % 8 == 0)
    const int bm0 = (swz / 13) * 128;
    const int nt  = swz % 13;
    const int bn0 = (nt < 12) ? nt * 80 : 920;
    const int cls0 = (nt < 12) ? nt * 8 : 92;
    const int tid = threadIdx.x, lane = tid & 63, wid = tid >> 6;
    const int ls = lane >> 4, lf = lane & 15;
    float* xsq_s = (float*)(smem + 20992);
    float* psq_s = (float*)(smem + 21504);
    if (tid < 128) xsq_s[tid] = xsq[bm0 + tid];
    if (tid < 80)  psq_s[tid] = psq[bn0 + tid];

    // A direct-load pointers: lane holds its MFMA A-frag rows
    const unsigned short* ga[2];
#pragma unroll
    for (int f = 0; f < 2; ++f)
        ga[f] = xb + (size_t)(bm0 + wid * 32 + f * 16 + lf) * FEAT + ls * 8;

    // B staging (rule 21): lane (r=lane>>3, cb=lane&7) loads logical col block
    // (cb ^ r) so the linear LDS write lands at the swizzled slot.
    const int sr = lane >> 3, scb = lane & 7;
    const int scol = ((scb ^ sr) << 3);
    const unsigned short* bptr[3];
#pragma unroll
    for (int j = 0; j < 3; ++j) {
        int cj = wid + j * 4;
        bptr[j] = epb + (size_t)(bn0 + (cj < 10 ? cj : 0) * 8 + sr) * FEAT + scol;
    }

    // swizzled B read offsets: addr = row*128 + ((CB ^ (row&7)) << 4)
    int raB[5];
#pragma unroll
    for (int f = 0; f < 5; ++f) raB[f] = (f * 16 + lf) * 128;
    const int sw = lf & 7;

    f32x4 acc[2][5] = {};
    short8 aC[2][2], aN[2][2];

    // prologue: A-frags for tile 0, stage B tile 0 into buf0
#pragma unroll
    for (int f = 0; f < 2; ++f)
#pragma unroll
        for (int k2 = 0; k2 < 2; ++k2)
            aC[f][k2] = *(const short8*)(ga[f] + k2 * 32);
#pragma unroll
    for (int j = 0; j < 3; ++j) {
        int cj = wid + j * 4;
        if (cj < 10) gload16(bptr[j], smem + cj * 1024);
    }
    __syncthreads();

#pragma unroll
    for (int t = 0; t < 16; ++t) {
        const char* base = (const char*)smem + (t & 1) * 10240;
        // 1) issue NEXT tile's A-frags (consumed next iteration)
        if (t < 15) {
#pragma unroll
            for (int f = 0; f < 2; ++f)
#pragma unroll
                for (int k2 = 0; k2 < 2; ++k2)
                    aN[f][k2] = *(const short8*)(ga[f] + (t + 1) * 64 + k2 * 32);
            // 2) stage next B tile into the other buffer (stays in flight)
            char* nb = (char*)smem + ((t + 1) & 1) * 10240;
#pragma unroll
            for (int j = 0; j < 3; ++j) {
                int cj = wid + j * 4;
                if (cj < 10) gload16(bptr[j] + (t + 1) * 64, nb + cj * 1024);
            }
        }
        // 3) compute from current A-regs + B buffer
#pragma unroll
        for (int k2 = 0; k2 < 2; ++k2) {
            const int off = (((k2 * 4 + ls) ^ sw) << 4);
            short8 b[5];
#pragma unroll
            for (int f = 0; f < 5; ++f)
                b[f] = *(const short8*)(base + raB[f] + off);
#pragma unroll
            for (int fm = 0; fm < 2; ++fm)
#pragma unroll
                for (int fn = 0; fn < 5; ++fn)
                    acc[fm][fn] = __builtin_amdgcn_mfma_f32_16x16x32_bf16(aC[fm][k2], b[fn], acc[fm][fn], 0, 0, 0);
        }
        // 4) single barrier (implicit vmcnt(0) drain lands AFTER compute)
        __syncthreads();
#pragma unroll
        for (int f = 0; f < 2; ++f)
#pragma unroll
            for (int k2 = 0; k2 < 2; ++k2)
                aC[f][k2] = aN[f][k2];
    }

    // epilogue: d = sqrt(max(xsq - 2*dot + psq, 0)); min over groups of 10.
    float* dls = (float*)smem;
    const int tr = ls * 4;
#pragma unroll
    for (int p = 0; p < 2; ++p) {
        __syncthreads();
#pragma unroll
        for (int fn = 0; fn < 5; ++fn) {
            int col = fn * 16 + lf;
            float pq = psq_s[col];
#pragma unroll
            for (int r = 0; r < 4; ++r) {
                float d2 = xsq_s[wid * 32 + p * 16 + tr + r] - 2.f * acc[p][fn][r] + pq;
                dls[(wid * 16 + tr + r) * 81 + col] = sqrtf(fmaxf(d2, 0.f));
            }
        }
        __syncthreads();
#pragma unroll
        for (int i = 0; i < 2; ++i) {
            int task = tid + i * 256;      // 512 tasks: 64 rows x 8 classes
            int rr = task >> 3, cl = task & 7;
            float m = 1e30f;
#pragma unroll
            for (int j = 0; j < 10; ++j) m = fminf(m, dls[rr * 81 + cl * 10 + j]);
            int grow = bm0 + (rr >> 4) * 32 + p * 16 + (rr & 15);
            out[(size_t)grow * NCLS + cls0 + cl] = m;
        }
    }
}

extern "C" void kernel_launch(void* const* d_in, const int* in_sizes, int n_in,
                              void* d_out, int out_size, void* d_ws, size_t ws_size,
                              hipStream_t stream) {
    const float* x      = (const float*)d_in[0];
    const float* protos = (const float*)d_in[1];
    const float* enc_w  = (const float*)d_in[2];
    const float* enc_b  = (const float*)d_in[3];
    float* out = (float*)d_out;
    char* ws = (char*)d_ws;

    unsigned short* xb  = (unsigned short*)ws;                   // 16384*1024*2 = 33554432
    unsigned short* epb = (unsigned short*)(ws + 33554432);      // 1000*1024*2 (2MB slot)
    unsigned short* prb = (unsigned short*)(ws + 35651584);      // 1024*1024*2  = 2097152
    unsigned short* wtb = (unsigned short*)(ws + 37748736);      // 1024*1024*2  = 2097152
    float* xsq = (float*)(ws + 39845888);                        // 16384*4
    float* psq = (float*)(ws + 39911424);                        // 1000*4

    hipMemsetAsync(psq, 0, (size_t)NALL * 4, stream);            // fused-psq atomics

    k_prep_all<<<6144, 256, 0, stream>>>(x, xb, xsq, protos, prb, enc_w, wtb);
    k_enc_gemm<<<256, 256, 0, stream>>>(prb, wtb, enc_b, epb, psq);
    k_main<<<1664, 256, 0, stream>>>(xb, epb, xsq, psq, out);
}

// Round 19
// 94.262 us; speedup vs baseline: 1.3324x; 1.3324x over previous
//
#include <hip/hip_runtime.h>
#include <hip/hip_bf16.h>
#include <stdint.h>

#define FEAT 1024
#define NALL 1000
#define NCLS 100

typedef __attribute__((ext_vector_type(8))) short short8;
typedef __attribute__((ext_vector_type(4))) float f32x4;
typedef __attribute__((ext_vector_type(4))) unsigned short us4;

__device__ __forceinline__ unsigned short f2bf(float f) {
    union { float f; uint32_t u; } v; v.f = f;
    uint32_t u = v.u;
    return (unsigned short)((u + 0x7FFFu + ((u >> 16) & 1u)) >> 16);
}

__device__ __forceinline__ void gload16(const void* g, void* l) {
    __builtin_amdgcn_global_load_lds((__attribute__((address_space(1))) void*)g,
                                     (__attribute__((address_space(3))) void*)l,
                                     16, 0, 0);
}

// K1 (merged prep): blocks [0,4096): x -> bf16 + row sum-sq
//                   blocks [4096,5120): protos -> bf16 (pad rows 1000.. = 0)
//                   blocks [5120,6144): enc_w transpose -> bf16 wt[n][k]=w[k][n]
//                   block 6144: zero psq (replaces hipMemsetAsync dispatch)
__global__ __launch_bounds__(256) void k_prep_all(const float* __restrict__ x,
                                                  unsigned short* __restrict__ xb,
                                                  float* __restrict__ xsq,
                                                  const float* __restrict__ p,
                                                  unsigned short* __restrict__ pb,
                                                  const float* __restrict__ w,
                                                  unsigned short* __restrict__ wt,
                                                  float* __restrict__ psq) {
    __shared__ float tile[32][33];
    int b = blockIdx.x;
    if (b < 4096) {
        int row = b * 4 + (threadIdx.x >> 6);
        int lane = threadIdx.x & 63;
        const float4* xr = (const float4*)(x + (size_t)row * FEAT);
        float s = 0.f;
#pragma unroll
        for (int i = 0; i < 4; ++i) {
            float4 v = xr[lane + i * 64];
            s += v.x * v.x + v.y * v.y + v.z * v.z + v.w * v.w;
            us4 o;
            o[0] = f2bf(v.x); o[1] = f2bf(v.y); o[2] = f2bf(v.z); o[3] = f2bf(v.w);
            *(us4*)(xb + (size_t)row * FEAT + (size_t)(lane + i * 64) * 4) = o;
        }
#pragma unroll
        for (int off = 32; off; off >>= 1) s += __shfl_xor(s, off);
        if (lane == 0) xsq[row] = s;
    } else if (b < 5120) {
        int row = b - 4096, t = threadIdx.x;
        us4 o;
        if (row < NALL) {
            float4 v = ((const float4*)(p + (size_t)row * FEAT))[t];
            o[0] = f2bf(v.x); o[1] = f2bf(v.y); o[2] = f2bf(v.z); o[3] = f2bf(v.w);
        } else {
            o[0] = 0; o[1] = 0; o[2] = 0; o[3] = 0;
        }
        *(us4*)(pb + (size_t)row * FEAT + (size_t)t * 4) = o;
    } else if (b < 6144) {
        int bb = b - 5120;
        int bx = bb & 31, by = bb >> 5;
        int tx = threadIdx.x & 31, ty = threadIdx.x >> 5;
#pragma unroll
        for (int i = 0; i < 4; ++i) {
            int r = by * 32 + ty + i * 8;
            tile[ty + i * 8][tx] = w[(size_t)r * FEAT + bx * 32 + tx];
        }
        __syncthreads();
#pragma unroll
        for (int i = 0; i < 4; ++i) {
            int r = bx * 32 + ty + i * 8;
            wt[(size_t)r * FEAT + by * 32 + tx] = f2bf(tile[tx][ty + i * 8]);
        }
    } else {
#pragma unroll
        for (int i = 0; i < 4; ++i) {
            int idx = threadIdx.x + i * 256;
            if (idx < NALL) psq[idx] = 0.f;
        }
    }
}

// K2: encoder GEMM ep = protos @ enc_w + b — 64x64 tiles, 256 blocks, with
// FUSED psq (bf16-rounded squares, shfl-reduced, one atomicAdd/row/wave).
// epb rows class-major permuted: n' = (n%100)*10 + n/100.
__global__ __launch_bounds__(256) void k_enc_gemm(const unsigned short* __restrict__ A,
                                                  const unsigned short* __restrict__ B,
                                                  const float* __restrict__ bias,
                                                  unsigned short* __restrict__ epb,
                                                  float* __restrict__ psq) {
    __shared__ __align__(16) char smem[16384];   // A [64][64] @0, B [64][64] @8192
    int bm0 = (blockIdx.x >> 4) * 64;
    int bn0 = (blockIdx.x & 15) * 64;
    int tid = threadIdx.x, lane = tid & 63, wid = tid >> 6;
    int wm = wid >> 1, wn = wid & 1;
    int ls = lane >> 4, lf = lane & 15;
    f32x4 acc[2][2] = {};
    for (int k0 = 0; k0 < FEAT; k0 += 64) {
        __syncthreads();
#pragma unroll
        for (int i = 0; i < 2; ++i) {
            int ci = wid + i * 4;
            int r = ci * 8 + (lane >> 3), c = (lane & 7) * 8;
            gload16(A + (size_t)(bm0 + r) * FEAT + k0 + c, smem + ci * 1024);
            gload16(B + (size_t)(bn0 + r) * FEAT + k0 + c, smem + 8192 + ci * 1024);
        }
        __syncthreads();
#pragma unroll
        for (int kk = 0; kk < 64; kk += 32) {
            short8 a[2], b[2];
#pragma unroll
            for (int f = 0; f < 2; ++f) {
                a[f] = *(const short8*)(smem + (wm * 32 + f * 16 + lf) * 128 + (kk + ls * 8) * 2);
                b[f] = *(const short8*)(smem + 8192 + (wn * 32 + f * 16 + lf) * 128 + (kk + ls * 8) * 2);
            }
#pragma unroll
            for (int fm = 0; fm < 2; ++fm)
#pragma unroll
                for (int fn = 0; fn < 2; ++fn)
                    acc[fm][fn] = __builtin_amdgcn_mfma_f32_16x16x32_bf16(a[fm], b[fn], acc[fm][fn], 0, 0, 0);
        }
    }
    int tr = ls * 4, tc = lf;
    float sq[2][4] = {};
#pragma unroll
    for (int fn = 0; fn < 2; ++fn) {
        int col = bn0 + wn * 32 + fn * 16 + tc;
        float bb = bias[col];
#pragma unroll
        for (int fm = 0; fm < 2; ++fm) {
#pragma unroll
            for (int r = 0; r < 4; ++r) {
                int row = bm0 + wm * 32 + fm * 16 + tr + r;
                if (row < NALL) {
                    unsigned short us = f2bf(acc[fm][fn][r] + bb);
                    union { uint32_t u; float f; } c; c.u = ((uint32_t)us) << 16;
                    sq[fm][r] += c.f * c.f;
                    int pr = (row % 100) * 10 + row / 100;
                    epb[(size_t)pr * FEAT + col] = us;
                }
            }
        }
    }
#pragma unroll
    for (int fm = 0; fm < 2; ++fm)
#pragma unroll
        for (int r = 0; r < 4; ++r) {
            float s = sq[fm][r];
            s += __shfl_xor(s, 1); s += __shfl_xor(s, 2);
            s += __shfl_xor(s, 4); s += __shfl_xor(s, 8);
            int row = bm0 + wm * 32 + fm * 16 + tr + r;
            if (lf == 0 && row < NALL) {
                int pr = (row % 100) * 10 + row / 100;
                atomicAdd(psq + pr, s);
            }
        }
}

// K3: main GEMM + fused sqrt + min-over-10 — frozen best structure (r12/r15).
// BM=128, BN=80, BK=64, 4 waves 4Mx1N, acc[2][5], 27KB LDS, 4 blocks/CU.
// 13 N-tiles, last at bn0=920 (classes 92-99; overlap cols written twice with
// identical values). Grid 128x13 = 1664.
__global__ __launch_bounds__(256, 4) void k_main(const unsigned short* __restrict__ xb,
                                                 const unsigned short* __restrict__ epb,
                                                 const float* __restrict__ xsq,
                                                 const float* __restrict__ psq,
                                                 float* __restrict__ out) {
    __shared__ __align__(16) char smem[27648];
    const int bid = blockIdx.x;                       // 1664 blocks
    const int swz = (bid & 7) * 208 + (bid >> 3);     // XCD swizzle (1664 % 8 == 0)
    const int bm0 = (swz / 13) * 128;
    const int nt  = swz % 13;
    const int bn0 = (nt < 12) ? nt * 80 : 920;
    const int cls0 = (nt < 12) ? nt * 8 : 92;
    const int tid = threadIdx.x, lane = tid & 63, wid = tid >> 6;
    const int ls = lane >> 4, lf = lane & 15;
    float* xsq_s = (float*)(smem + 26624);
    float* psq_s = (float*)(smem + 27136);
    if (tid < 128) xsq_s[tid] = xsq[bm0 + tid];
    if (tid < 80)  psq_s[tid] = psq[bn0 + tid];

    // staging (rule 21): lane (r=lane>>3, cb=lane&7) loads logical col block
    // (cb ^ r) so the linear LDS write lands at the swizzled slot.
    const int sr = lane >> 3, scb = lane & 7;
    const int scol = ((scb ^ sr) << 3);
    const unsigned short* aptr[4];
    const unsigned short* bptr[3];
#pragma unroll
    for (int i = 0; i < 4; ++i)
        aptr[i] = xb + (size_t)(bm0 + (wid + i * 4) * 8 + sr) * FEAT + scol;
#pragma unroll
    for (int j = 0; j < 3; ++j) {
        int cj = wid + j * 4;
        bptr[j] = epb + (size_t)(bn0 + (cj < 10 ? cj : 0) * 8 + sr) * FEAT + scol;
    }

    // swizzled read offsets: addr = row*128 + ((CB ^ (row&7)) << 4)
    int raA[2], raB[5];
#pragma unroll
    for (int f = 0; f < 2; ++f) raA[f] = (wid * 32 + f * 16 + lf) * 128;
#pragma unroll
    for (int f = 0; f < 5; ++f) raB[f] = 16384 + (f * 16 + lf) * 128;
    const int sw = lf & 7;

    f32x4 acc[2][5] = {};

    for (int t = 0; t < 16; ++t) {
        __syncthreads();   // previous tile's reads done before overwrite
#pragma unroll
        for (int i = 0; i < 4; ++i)
            gload16(aptr[i], smem + (wid + i * 4) * 1024);
#pragma unroll
        for (int j = 0; j < 3; ++j) {
            int cj = wid + j * 4;
            if (cj < 10) gload16(bptr[j], smem + 16384 + cj * 1024);
        }
#pragma unroll
        for (int i = 0; i < 4; ++i) aptr[i] += 64;
#pragma unroll
        for (int j = 0; j < 3; ++j) bptr[j] += 64;
        __syncthreads();   // drains vmcnt -> staged data visible
#pragma unroll
        for (int kk2 = 0; kk2 < 2; ++kk2) {
            const int off = (((kk2 * 4 + ls) ^ sw) << 4);
            short8 a[2], b[5];
#pragma unroll
            for (int f = 0; f < 2; ++f)
                a[f] = *(const short8*)(smem + raA[f] + off);
#pragma unroll
            for (int f = 0; f < 5; ++f)
                b[f] = *(const short8*)(smem + raB[f] + off);
#pragma unroll
            for (int fm = 0; fm < 2; ++fm)
#pragma unroll
                for (int fn = 0; fn < 5; ++fn)
                    acc[fm][fn] = __builtin_amdgcn_mfma_f32_16x16x32_bf16(a[fm], b[fn], acc[fm][fn], 0, 0, 0);
        }
    }

    // epilogue: d = sqrt(max(xsq - 2*dot + psq, 0)); min over groups of 10.
    float* dls = (float*)smem;
    const int tr = ls * 4;
#pragma unroll
    for (int p = 0; p < 2; ++p) {
        __syncthreads();
#pragma unroll
        for (int fn = 0; fn < 5; ++fn) {
            int col = fn * 16 + lf;
            float pq = psq_s[col];
#pragma unroll
            for (int r = 0; r < 4; ++r) {
                float d2 = xsq_s[wid * 32 + p * 16 + tr + r] - 2.f * acc[p][fn][r] + pq;
                dls[(wid * 16 + tr + r) * 81 + col] = sqrtf(fmaxf(d2, 0.f));
            }
        }
        __syncthreads();
#pragma unroll
        for (int i = 0; i < 2; ++i) {
            int task = tid + i * 256;      // 512 tasks: 64 rows x 8 classes
            int rr = task >> 3, cl = task & 7;
            float m = 1e30f;
#pragma unroll
            for (int j = 0; j < 10; ++j) m = fminf(m, dls[rr * 81 + cl * 10 + j]);
            int grow = bm0 + (rr >> 4) * 32 + p * 16 + (rr & 15);
            out[(size_t)grow * NCLS + cls0 + cl] = m;
        }
    }
}

extern "C" void kernel_launch(void* const* d_in, const int* in_sizes, int n_in,
                              void* d_out, int out_size, void* d_ws, size_t ws_size,
                              hipStream_t stream) {
    const float* x      = (const float*)d_in[0];
    const float* protos = (const float*)d_in[1];
    const float* enc_w  = (const float*)d_in[2];
    const float* enc_b  = (const float*)d_in[3];
    float* out = (float*)d_out;
    char* ws = (char*)d_ws;

    unsigned short* xb  = (unsigned short*)ws;                   // 16384*1024*2 = 33554432
    unsigned short* epb = (unsigned short*)(ws + 33554432);      // 1000*1024*2 (2MB slot)
    unsigned short* prb = (unsigned short*)(ws + 35651584);      // 1024*1024*2  = 2097152
    unsigned short* wtb = (unsigned short*)(ws + 37748736);      // 1024*1024*2  = 2097152
    float* xsq = (float*)(ws + 39845888);                        // 16384*4
    float* psq = (float*)(ws + 39911424);                        // 1000*4

    k_prep_all<<<6145, 256, 0, stream>>>(x, xb, xsq, protos, prb, enc_w, wtb, psq);
    k_enc_gemm<<<256, 256, 0, stream>>>(prb, wtb, enc_b, epb, psq);
    k_main<<<1664, 256, 0, stream>>>(xb, epb, xsq, psq, out);
}